// Round 4
// baseline (676.502 us; speedup 1.0000x reference)
//
#include <hip/hip_runtime.h>
#include <hip/hip_bf16.h>

typedef __hip_bfloat16 bf16;
typedef __bf16 bf16x8 __attribute__((ext_vector_type(8)));
typedef float f32x4 __attribute__((ext_vector_type(4)));
typedef short short8 __attribute__((ext_vector_type(8)));

#define NH 24
#define NKV 8
#define HD 128
#define SEQ 2048
#define NREP 3

__device__ inline void gload16(const void* g, void* l) {
  __builtin_amdgcn_global_load_lds(
      (const __attribute__((address_space(1))) void*)g,
      (__attribute__((address_space(3))) void*)l, 16, 0, 0);
}

// ---------------- cast f32 -> bf16 (vectorized) ----------------
__global__ void cast_f32_bf16(const float* __restrict__ in, bf16* __restrict__ out, int n4) {
  int i = blockIdx.x * 256 + threadIdx.x;
  if (i >= n4) return;
  float4 v = reinterpret_cast<const float4*>(in)[i];
  ushort4 u;
  u.x = __builtin_bit_cast(unsigned short, __float2bfloat16(v.x));
  u.y = __builtin_bit_cast(unsigned short, __float2bfloat16(v.y));
  u.z = __builtin_bit_cast(unsigned short, __float2bfloat16(v.z));
  u.w = __builtin_bit_cast(unsigned short, __float2bfloat16(v.w));
  reinterpret_cast<ushort4*>(out)[i] = u;
}

// ---------------- transpose + cast: W (KxN f32) -> WT (NxK bf16) ----------------
__global__ void transpose_cast(const float* __restrict__ W, bf16* __restrict__ WT, int K, int N) {
  __shared__ bf16 tile[32][33];
  int n0 = blockIdx.x * 32, k0 = blockIdx.y * 32;
  int tx = threadIdx.x, ty = threadIdx.y;  // (32, 8)
#pragma unroll
  for (int i = 0; i < 4; ++i) {
    int kl = ty + i * 8;
    tile[kl][tx] = __float2bfloat16(W[(size_t)(k0 + kl) * N + n0 + tx]);
  }
  __syncthreads();
#pragma unroll
  for (int i = 0; i < 4; ++i) {
    int nl = ty + i * 8;
    WT[(size_t)(n0 + nl) * K + k0 + tx] = tile[tx][nl];
  }
}

// ---------------- V global transpose: Vb (b*S rows, g*HD cols) -> Vt[b][g][d][s] ----------------
__global__ void transpose_v(const bf16* __restrict__ Vb, bf16* __restrict__ Vt) {
  __shared__ bf16 tile[32][33];
  int bg = blockIdx.z;
  int b = bg >> 3, g = bg & 7;
  int s0 = blockIdx.x * 32, d0 = blockIdx.y * 32;
  int tx = threadIdx.x, ty = threadIdx.y;  // (32, 8)
#pragma unroll
  for (int i = 0; i < 4; ++i) {
    int sl = ty + i * 8;
    tile[sl][tx] = Vb[(size_t)(b * SEQ + s0 + sl) * (NKV * HD) + g * HD + d0 + tx];
  }
  __syncthreads();
#pragma unroll
  for (int i = 0; i < 4; ++i) {
    int dl = ty + i * 8;
    Vt[((size_t)(b * NKV + g) * HD + d0 + dl) * SEQ + s0 + tx] = tile[tx][dl];
  }
}

// ---------------- RoPE in-place on bf16 buffer ----------------
__global__ void rope_kernel(bf16* __restrict__ T, const float* __restrict__ cosT,
                            const float* __restrict__ sinT, int H, int total) {
  int i = blockIdx.x * 256 + threadIdx.x;
  if (i >= total) return;
  int d2 = i & 63;
  int rh = i >> 6;
  int r = rh / H;
  int s = r & (SEQ - 1);
  float c = cosT[s * 64 + d2];
  float sn = sinT[s * 64 + d2];
  bf16* p = T + (size_t)rh * HD + d2 * 2;
  float a = __bfloat162float(p[0]);
  float b = __bfloat162float(p[1]);
  p[0] = __float2bfloat16(a * c - b * sn);
  p[1] = __float2bfloat16(a * sn + b * c);
}

// ---------------- GEMM: C[M,N] = A[M,K] @ BT[N,K]^T  (m97-style) ----------------
template <bool OUT_BF16>
__global__ __launch_bounds__(256) void gemm_bt(const bf16* __restrict__ A,
                                               const bf16* __restrict__ BT,
                                               void* __restrict__ Cv,
                                               int M, int N, int K) {
  __shared__ bf16 lsA[128 * 32];
  __shared__ bf16 lsB[128 * 32];
  int m0 = blockIdx.y * 128, n0 = blockIdx.x * 128;
  int tid = threadIdx.x;
  int w = tid >> 6, lane = tid & 63;
  int wm = w >> 1, wn = w & 1;
  int lr = lane & 15, lk = lane >> 4;
  f32x4 acc[4][4] = {};
  for (int k0 = 0; k0 < K; k0 += 32) {
    __syncthreads();
#pragma unroll
    for (int is = 0; is < 2; ++is) {
      int slot = is * 256 + tid;
      int row = slot >> 2, kc = slot & 3;
      gload16(A + (size_t)(m0 + row) * K + k0 + kc * 8, lsA + slot * 8);
      gload16(BT + (size_t)(n0 + row) * K + k0 + kc * 8, lsB + slot * 8);
    }
    __syncthreads();
    bf16x8 aF[4], bF[4];
#pragma unroll
    for (int t = 0; t < 4; ++t) {
      aF[t] = *reinterpret_cast<const bf16x8*>(&lsA[(wm * 64 + t * 16 + lr) * 32 + lk * 8]);
      bF[t] = *reinterpret_cast<const bf16x8*>(&lsB[(wn * 64 + t * 16 + lr) * 32 + lk * 8]);
    }
#pragma unroll
    for (int mt = 0; mt < 4; ++mt)
#pragma unroll
      for (int nt = 0; nt < 4; ++nt)
        acc[mt][nt] = __builtin_amdgcn_mfma_f32_16x16x32_bf16(aF[mt], bF[nt], acc[mt][nt], 0, 0, 0);
  }
#pragma unroll
  for (int mt = 0; mt < 4; ++mt)
#pragma unroll
    for (int nt = 0; nt < 4; ++nt)
#pragma unroll
      for (int r = 0; r < 4; ++r) {
        int m = m0 + wm * 64 + mt * 16 + lk * 4 + r;
        int n = n0 + wn * 64 + nt * 16 + lr;
        float v = acc[mt][nt][r];
        if (OUT_BF16)
          reinterpret_cast<bf16*>(Cv)[(size_t)m * N + n] = __float2bfloat16(v);
        else
          reinterpret_cast<float*>(Cv)[(size_t)m * N + n] = v;
      }
}

// ---------------- Flash attention (causal, GQA) ----------------
// 4 waves x 16 q-rows = 64 q-rows/block; KV tile = 64 rows, double-buffered.
// Klds: [64 s][16 chunks of 8 bf16], chunk XOR-swizzled by (s&7)  (both-sides swizzle)
// Vlds: [128 d][8 chunks of 8 bf16 (s)], chunk XOR-swizzled by (d&7)
// Plds: per-wave [16 q][8 chunks of 8 bf16 (k)], chunk XOR-swizzled by (q&7)
#define SCALE_LOG2 0.12751745f  // (1/sqrt(128)) * log2(e)

__global__ __launch_bounds__(256, 2) void attn_kernel(const bf16* __restrict__ Q,
                                                      const bf16* __restrict__ K,
                                                      const bf16* __restrict__ Vt,
                                                      bf16* __restrict__ O) {
  __shared__ bf16 Klds[2][64 * 128];   // 2 x 16 KB
  __shared__ bf16 Vlds[2][128 * 64];   // 2 x 16 KB
  __shared__ bf16 Plds[4][16 * 64];    // 8 KB
  int qt = (int)gridDim.x - 1 - (int)blockIdx.x;   // big-work blocks first
  int bh = blockIdx.y;
  int b = bh / NH, h = bh % NH, g = h / NREP;
  int tid = threadIdx.x, w = tid >> 6, lane = tid & 63;
  int lr = lane & 15, lk = lane >> 4;
  int q0 = qt * 64 + w * 16;  // wave's q base

  // --- Q fragments (A operand): rows q0+lr, k = kk*32 + lk*8 + j ---
  bf16x8 aQ[4];
  {
    const bf16* qrow = Q + ((size_t)(b * SEQ) + q0 + lr) * (NH * HD) + h * HD;
#pragma unroll
    for (int kk = 0; kk < 4; ++kk)
      aQ[kk] = *reinterpret_cast<const bf16x8*>(qrow + kk * 32 + lk * 8);
  }

  // --- staging offsets (tile-independent) ---
  const bf16* kvK = K + ((size_t)b * SEQ * NKV + g) * HD;
  const bf16* kvVt = Vt + ((size_t)(b * NKV + g) * HD) * SEQ;
  int koff[4], kslot[4];
#pragma unroll
  for (int i = 0; i < 4; ++i) {
    int t = i * 256 + tid;          // 1024 K slots of 8 bf16
    int row = t >> 4, c = t & 15;
    int sc = c ^ (row & 7);         // pre-swizzled source chunk
    koff[i] = row * (NKV * HD) + sc * 8;
    kslot[i] = t * 8;
  }
  int voff[4], vslot[4];
#pragma unroll
  for (int i = 0; i < 4; ++i) {
    int t = i * 256 + tid;          // 1024 V slots of 8 bf16
    int d = t >> 3, c = t & 7;
    int sc = c ^ (d & 7);
    voff[i] = d * SEQ + sc * 8;
    vslot[i] = t * 8;
  }

  f32x4 Oacc[8] = {};
  float m_s[4], l_s[4];
#pragma unroll
  for (int r = 0; r < 4; ++r) { m_s[r] = -1e30f; l_s[r] = 0.f; }

  bf16* pb = Plds[w];
  const int jlast = qt * 64;  // last tile base

  // ---- prologue: stage tile 0 into buffer 0 ----
  {
#pragma unroll
    for (int i = 0; i < 4; ++i) gload16(kvK + koff[i], Klds[0] + kslot[i]);
#pragma unroll
    for (int i = 0; i < 4; ++i) gload16(kvVt + voff[i], Vlds[0] + vslot[i]);
  }

  int cur = 0;
  for (int j0 = 0; j0 <= jlast; j0 += 64, cur ^= 1) {
    __builtin_amdgcn_s_barrier();   // bar A: all reads of buf[cur^1] (tile j0-64) done
    {
      int jn = j0 + 64 <= jlast ? j0 + 64 : jlast;  // last iter: dummy restage
      const bf16* ks = kvK + (size_t)jn * (NKV * HD);
      const bf16* vs = kvVt + jn;
      bf16* kd = Klds[cur ^ 1];
      bf16* vd = Vlds[cur ^ 1];
#pragma unroll
      for (int i = 0; i < 4; ++i) gload16(ks + koff[i], kd + kslot[i]);
#pragma unroll
      for (int i = 0; i < 4; ++i) gload16(vs + voff[i], vd + vslot[i]);
    }
    asm volatile("s_waitcnt vmcnt(8)" ::: "memory");  // tile j0's 8 loads complete
    __builtin_amdgcn_sched_barrier(0);
    __builtin_amdgcn_s_barrier();   // bar B: buf[cur] ready for all waves
    if (j0 > q0 + 15) continue;     // causal skip (barriers already passed)

    const bf16* Kb = Klds[cur];
    const bf16* Vb = Vlds[cur];

    // ---- QK^T : 4 n-tiles of 16 cols ----
    f32x4 sc4[4] = {};
#pragma unroll
    for (int kk = 0; kk < 4; ++kk) {
#pragma unroll
      for (int nt = 0; nt < 4; ++nt) {
        int jrow = nt * 16 + lr;
        int pos = (4 * kk + lk) ^ (lr & 7);
        bf16x8 bK = *reinterpret_cast<const bf16x8*>(&Kb[jrow * 128 + pos * 8]);
        sc4[nt] = __builtin_amdgcn_mfma_f32_16x16x32_bf16(aQ[kk], bK, sc4[nt], 0, 0, 0);
      }
    }

    // ---- mask + online softmax (log2 domain) ----
    float sv[4][4], mx[4];
#pragma unroll
    for (int r = 0; r < 4; ++r) mx[r] = -3e38f;
#pragma unroll
    for (int nt = 0; nt < 4; ++nt) {
      int col = j0 + nt * 16 + lr;
#pragma unroll
      for (int r = 0; r < 4; ++r) {
        int row = q0 + lk * 4 + r;
        sv[nt][r] = (col > row) ? -3e38f : sc4[nt][r] * SCALE_LOG2;
        mx[r] = fmaxf(mx[r], sv[nt][r]);
      }
    }
#pragma unroll
    for (int d = 1; d < 16; d <<= 1)
#pragma unroll
      for (int r = 0; r < 4; ++r) mx[r] = fmaxf(mx[r], __shfl_xor(mx[r], d, 64));

    // exact defer-max: rescale only if some row's max grew
    bool grow = false;
#pragma unroll
    for (int r = 0; r < 4; ++r) grow = grow || (mx[r] > m_s[r]);
    if (__any(grow)) {
      float alpha[4];
#pragma unroll
      for (int r = 0; r < 4; ++r) {
        float mn = fmaxf(m_s[r], mx[r]);
        alpha[r] = exp2f(m_s[r] - mn);
        m_s[r] = mn;
        l_s[r] *= alpha[r];
      }
#pragma unroll
      for (int nc = 0; nc < 8; ++nc)
#pragma unroll
        for (int r = 0; r < 4; ++r) Oacc[nc][r] *= alpha[r];
    }
    float p[4][4], rs[4];
#pragma unroll
    for (int r = 0; r < 4; ++r) {
      rs[r] = 0.f;
#pragma unroll
      for (int nt = 0; nt < 4; ++nt) {
        p[nt][r] = exp2f(sv[nt][r] - m_s[r]);
        rs[r] += p[nt][r];
      }
    }
#pragma unroll
    for (int d = 1; d < 16; d <<= 1)
#pragma unroll
      for (int r = 0; r < 4; ++r) rs[r] += __shfl_xor(rs[r], d, 64);
#pragma unroll
    for (int r = 0; r < 4; ++r) l_s[r] += rs[r];

    // ---- P -> wave-private swizzled LDS ----
#pragma unroll
    for (int nt = 0; nt < 4; ++nt)
#pragma unroll
      for (int r = 0; r < 4; ++r) {
        int row = lk * 4 + r;
        int c = nt * 16 + lr;
        pb[row * 64 + (((c >> 3) ^ (row & 7)) * 8) + (c & 7)] = __float2bfloat16(p[nt][r]);
      }
    asm volatile("s_waitcnt lgkmcnt(0)" ::: "memory");
    __builtin_amdgcn_sched_barrier(0);

    // ---- O += P @ V  (V fragments: contiguous bf16x8 along s from Vlds) ----
#pragma unroll
    for (int kb = 0; kb < 2; ++kb) {
      int px = ((kb * 4 + lk) ^ (lr & 7)) * 8;
      bf16x8 aP = *reinterpret_cast<const bf16x8*>(&pb[lr * 64 + px]);
#pragma unroll
      for (int nc = 0; nc < 8; ++nc) {
        bf16x8 bV = *reinterpret_cast<const bf16x8*>(&Vb[(nc * 16 + lr) * 64 + px]);
        Oacc[nc] = __builtin_amdgcn_mfma_f32_16x16x32_bf16(aP, bV, Oacc[nc], 0, 0, 0);
      }
    }
  }
  asm volatile("s_waitcnt vmcnt(0)" ::: "memory");  // drain dummy restage before endpgm

  // ---- epilogue ----
#pragma unroll
  for (int r = 0; r < 4; ++r) {
    float inv = 1.0f / l_s[r];
    size_t rowoff = ((size_t)(b * SEQ) + q0 + lk * 4 + r) * (NH * HD) + h * HD;
#pragma unroll
    for (int nc = 0; nc < 8; ++nc)
      O[rowoff + nc * 16 + lr] = __float2bfloat16(Oacc[nc][r] * inv);
  }
}

extern "C" void kernel_launch(void* const* d_in, const int* in_sizes, int n_in,
                              void* d_out, int out_size, void* d_ws, size_t ws_size,
                              hipStream_t stream) {
  const float* x = (const float*)d_in[0];
  const float* wq = (const float*)d_in[1];
  const float* wk = (const float*)d_in[2];
  const float* wv = (const float*)d_in[3];
  const float* wo = (const float*)d_in[4];
  const float* fc = (const float*)d_in[5];
  const float* fs = (const float*)d_in[6];
  float* out = (float*)d_out;
  (void)in_sizes; (void)n_in; (void)out_size; (void)ws_size;

  const int R = 2 * SEQ;
  const int DIMc = 3072;
  const int NQ = NH * HD;
  const int NKd = NKV * HD;

  char* ws = (char*)d_ws;
  bf16* xb = (bf16*)ws;   ws += (size_t)R * DIMc * 2;
  bf16* wqT = (bf16*)ws;  ws += (size_t)NQ * DIMc * 2;
  bf16* wkT = (bf16*)ws;  ws += (size_t)NKd * DIMc * 2;
  bf16* wvT = (bf16*)ws;  ws += (size_t)NKd * DIMc * 2;
  bf16* woT = (bf16*)ws;  ws += (size_t)DIMc * NQ * 2;
  bf16* Qb = (bf16*)ws;   ws += (size_t)R * NQ * 2;
  bf16* Kb = (bf16*)ws;   ws += (size_t)R * NKd * 2;
  bf16* Vb = (bf16*)ws;   ws += (size_t)R * NKd * 2;
  bf16* Ob = (bf16*)ws;   ws += (size_t)R * NQ * 2;
  bf16* VtG = xb;  // aliases xb: xb is dead after the V projection GEMM

  {
    int n4 = R * DIMc / 4;
    cast_f32_bf16<<<n4 / 256, 256, 0, stream>>>(x, xb, n4);
  }
  transpose_cast<<<dim3(NQ / 32, DIMc / 32), dim3(32, 8), 0, stream>>>(wq, wqT, DIMc, NQ);
  transpose_cast<<<dim3(NKd / 32, DIMc / 32), dim3(32, 8), 0, stream>>>(wk, wkT, DIMc, NKd);
  transpose_cast<<<dim3(NKd / 32, DIMc / 32), dim3(32, 8), 0, stream>>>(wv, wvT, DIMc, NKd);
  transpose_cast<<<dim3(DIMc / 32, NQ / 32), dim3(32, 8), 0, stream>>>(wo, woT, NQ, DIMc);
  gemm_bt<true><<<dim3(NQ / 128, R / 128), 256, 0, stream>>>(xb, wqT, Qb, R, NQ, DIMc);
  gemm_bt<true><<<dim3(NKd / 128, R / 128), 256, 0, stream>>>(xb, wkT, Kb, R, NKd, DIMc);
  gemm_bt<true><<<dim3(NKd / 128, R / 128), 256, 0, stream>>>(xb, wvT, Vb, R, NKd, DIMc);
  // V -> Vt[b][g][d][s]  (xb region; xb no longer needed)
  transpose_v<<<dim3(SEQ / 32, HD / 32, 2 * NKV), dim3(32, 8), 0, stream>>>(Vb, VtG);
  {
    int totQ = R * NH * 64;
    rope_kernel<<<totQ / 256, 256, 0, stream>>>(Qb, fc, fs, NH, totQ);
    int totK = R * NKV * 64;
    rope_kernel<<<totK / 256, 256, 0, stream>>>(Kb, fc, fs, NKV, totK);
  }
  attn_kernel<<<dim3(SEQ / 64, 2 * NH), 256, 0, stream>>>(Qb, Kb, VtG, Ob);
  gemm_bt<false><<<dim3(DIMc / 128, R / 128), 256, 0, stream>>>(Ob, woT, out, R, DIMc, NQ);
}